// Round 10
// baseline (372.312 us; speedup 1.0000x reference)
//
#include <hip/hip_runtime.h>
#include <math.h>

#define N        50000
#define IN_DIM   256
#define H_DIM    96
#define POS_DIM  32
#define KCH      64
#define M        128
#define NE       800000
#define OUT_DIM  40
#define HID      128
#define NSCAN    196             // ceil(N/256)
#define NTILES   ((N + 63) / 64) // 782
#define NBK      391             // ceil(N/128) buckets of 128 nodes
#define BKCAP    2560            // bucket edge cap
#define NSCATB   512             // bscatter blocks
#define SREG     1563            // edges per bscatter block

typedef __attribute__((ext_vector_type(8))) short short8v;
typedef __attribute__((ext_vector_type(4))) float float4v;

// ---------- bf16 helpers ----------
__device__ __forceinline__ unsigned short f2bf(float f){
  unsigned u = __float_as_uint(f);
  u += 0x7fffu + ((u >> 16) & 1u);      // RNE
  return (unsigned short)(u >> 16);
}
__device__ __forceinline__ float bf_lo(unsigned u){ return __uint_as_float(u << 16); }
__device__ __forceinline__ float bf_hi(unsigned u){ return __uint_as_float(u & 0xffff0000u); }

// ---------- float <-> ordered-uint encoding for atomic min/max ----------
__device__ __forceinline__ unsigned enc_key(float f){
  unsigned u = __float_as_uint(f);
  return (u & 0x80000000u) ? ~u : (u | 0x80000000u);
}
__device__ __forceinline__ float dec_key(unsigned k){
  unsigned u = (k & 0x80000000u) ? (k ^ 0x80000000u) : ~k;
  return __uint_as_float(u);
}

// ---------- init ----------
__global__ void k_init(unsigned* __restrict__ encmn, unsigned* __restrict__ encmx,
                       short* __restrict__ WT_pos, float* __restrict__ bias_pos,
                       int* __restrict__ bkt_cnt){
  int i = blockIdx.x*blockDim.x + threadIdx.x;
  if (i < M){ encmn[i] = 0xFFFFFFFFu; encmx[i] = 0u; bias_pos[i] = 0.f; }
  if (i < M*M) WT_pos[i] = 0;
  if (i < NBK) bkt_cnt[i] = 0;
}

// ---------- per-column min/max of eigenvectors (parallel, float4) ----------
__global__ __launch_bounds__(256) void k_colminmax(const float* __restrict__ ev,
    unsigned* __restrict__ encmn, unsigned* __restrict__ encmx){
  __shared__ float4 smn[256], smx[256];
  int tid = threadIdx.x;
  int cg  = tid & 31;
  int rs  = blockIdx.x*8 + (tid >> 5);
  int stride = gridDim.x*8;
  float4 mn = make_float4( 3.4e38f,  3.4e38f,  3.4e38f,  3.4e38f);
  float4 mx = make_float4(-3.4e38f, -3.4e38f, -3.4e38f, -3.4e38f);
  #pragma unroll 4
  for (int r = rs; r < N; r += stride){
    float4 v = *(const float4*)&ev[(size_t)r*M + cg*4];
    mn.x = fminf(mn.x, v.x); mn.y = fminf(mn.y, v.y);
    mn.z = fminf(mn.z, v.z); mn.w = fminf(mn.w, v.w);
    mx.x = fmaxf(mx.x, v.x); mx.y = fmaxf(mx.y, v.y);
    mx.z = fmaxf(mx.z, v.z); mx.w = fmaxf(mx.w, v.w);
  }
  smn[tid] = mn; smx[tid] = mx;
  __syncthreads();
  for (int s = 128; s >= 32; s >>= 1){
    if (tid < s){
      float4 a = smn[tid], b = smn[tid + s];
      smn[tid] = make_float4(fminf(a.x,b.x), fminf(a.y,b.y), fminf(a.z,b.z), fminf(a.w,b.w));
      float4 c = smx[tid], d = smx[tid + s];
      smx[tid] = make_float4(fmaxf(c.x,d.x), fmaxf(c.y,d.y), fmaxf(c.z,d.z), fmaxf(c.w,d.w));
    }
    __syncthreads();
  }
  if (tid < 32){
    float4 a = smn[tid], b = smx[tid];
    atomicMin(&encmn[tid*4+0], enc_key(a.x));
    atomicMin(&encmn[tid*4+1], enc_key(a.y));
    atomicMin(&encmn[tid*4+2], enc_key(a.z));
    atomicMin(&encmn[tid*4+3], enc_key(a.w));
    atomicMax(&encmx[tid*4+0], enc_key(b.x));
    atomicMax(&encmx[tid*4+1], enc_key(b.y));
    atomicMax(&encmx[tid*4+2], enc_key(b.z));
    atomicMax(&encmx[tid*4+3], enc_key(b.w));
  }
}

// ---------- Chebyshev PE (eig min/max folded) + all weight prep (folded) ----------
// grid MUST be 16 blocks x 256 threads (4096 threads)
__global__ __launch_bounds__(256) void k_pe(
    const float* __restrict__ eigval, const float* __restrict__ alpha,
    const unsigned* __restrict__ encmn, const unsigned* __restrict__ encmx,
    const float* __restrict__ Wf, const float* __restrict__ bfeat,
    const float* __restrict__ Wl1, const float* __restrict__ Wr1,
    const float* __restrict__ Wl2, const float* __restrict__ Wr2,
    const float* __restrict__ Wro, const float* __restrict__ bro,
    short* __restrict__ WT_pos, float* __restrict__ pe_raw, float* __restrict__ pe_out,
    short* __restrict__ WTf, float* __restrict__ biasf,
    short* __restrict__ Wc1, short* __restrict__ Wc2,
    short* __restrict__ WTro, float* __restrict__ biasro){
  __shared__ float rmn[128], rmx[128];
  int tid = threadIdx.x;
  if (tid < 128){ float v = eigval[tid]; rmn[tid] = v; rmx[tid] = v; }
  __syncthreads();
  for (int s = 64; s; s >>= 1){
    if (tid < s){ rmn[tid] = fminf(rmn[tid], rmn[tid+s]); rmx[tid] = fmaxf(rmx[tid], rmx[tid+s]); }
    __syncthreads();
  }
  float lmin = rmn[0], lmax = rmx[0];
  int g = blockIdx.x*256 + tid;   // 0..4095
  int m = g >> 5, p = g & 31;
  float v = eigval[m];
  float lam = (v - lmin)/(lmax - lmin)*2.0f - 1.0f;
  lam = fminf(1.0f, fmaxf(-1.0f, lam));
  float t0 = 1.0f, t1 = lam;
  float acc = alpha[p] + lam*alpha[POS_DIM + p];
  float two_lam = lam + lam;
  #pragma unroll
  for (int k = 2; k < KCH; ++k){
    float t2 = fmaf(two_lam, t1, -t0);
    acc = fmaf(t2, alpha[k*POS_DIM + p], acc);
    t0 = t1; t1 = t2;
  }
  pe_out[g] = acc;
  pe_raw[g] = acc;
  float cmn = dec_key(encmn[m]);
  float cmx = dec_key(encmx[m]);
  float A = 2.0f/(cmx - cmn);
  WT_pos[p*M + m] = (short)f2bf(A*acc);
  // ---- folded weight prep (grid-stride over 4096 threads) ----
  for (int i = g; i < 128*256; i += 4096){
    int c = i >> 8, k = i & 255;
    WTf[i] = (c < H_DIM) ? (short)f2bf(Wf[c*IN_DIM + k]) : (short)0;
    Wc1[i] = (short)f2bf((k < HID) ? Wl1[c*HID + k] : Wr1[c*HID + k - HID]);
    Wc2[i] = (short)f2bf((k < HID) ? Wl2[c*HID + k] : Wr2[c*HID + k - HID]);
  }
  for (int i = g; i < 48*128; i += 4096){
    int c = i >> 7, k = i & 127;
    WTro[i] = (c < OUT_DIM) ? (short)f2bf(Wro[c*HID + k]) : (short)0;
  }
  if (g < 128) biasf[g] = (g < H_DIM) ? bfeat[g] : 0.f;
  if (g >= 128 && g < 176) biasro[g - 128] = (g - 128 < OUT_DIM) ? bro[g - 128] : 0.f;
}

// ---------- bias fold: bias_p = sum_m B_m * pe[m][p]  (deterministic) ----------
__global__ __launch_bounds__(256) void k_bias(
    const unsigned* __restrict__ encmn, const unsigned* __restrict__ encmx,
    const float* __restrict__ pe_raw, float* __restrict__ bias_pos){
  __shared__ float s[256];
  int tid = threadIdx.x;
  int p = tid >> 3, c = tid & 7;
  float sum = 0.f;
  for (int m = c*16; m < c*16 + 16; ++m){
    float cmn = dec_key(encmn[m]);
    float cmx = dec_key(encmx[m]);
    float A = 2.0f/(cmx - cmn);
    float B = -cmn*A - 1.0f;
    sum += B*pe_raw[m*POS_DIM + p];
  }
  s[tid] = sum;
  __syncthreads();
  if (c == 0){
    float t = 0.f;
    #pragma unroll
    for (int j = 0; j < 8; ++j) t += s[p*8 + j];
    bias_pos[p] = t;
  }
}

// ---------- fused input GEMM: h0 = [x@Wf.T + bf | ev@pe' + bias_p] ----------
__global__ __launch_bounds__(256) void k_gemm_in(
    const float* __restrict__ x, const float* __restrict__ ev,
    const short* __restrict__ WTf, const float* __restrict__ biasf,
    const short* __restrict__ WT_pos, const float* __restrict__ bias_pos,
    unsigned short* __restrict__ outp)
{
  __shared__ short a_lds[64*384];   // 48 KiB
  int tid = threadIdx.x;
  int wid = tid >> 6, lane = tid & 63;
  int lrow = lane & 15, lk = (lane >> 4)*8;
  bool isPos = (wid == 3);

  short8v bfragF[8][2];
  short8v bfragP[4][2];
  float b0, b1;
  if (!isPos){
    int colBase = wid*32;
    #pragma unroll
    for (int s = 0; s < 8; ++s)
      #pragma unroll
      for (int ct = 0; ct < 2; ++ct){
        int col = colBase + ct*16 + lrow;
        bfragF[s][ct] = *(const short8v*)&WTf[col*256 + s*32 + lk];
      }
    b0 = biasf[colBase + lrow]; b1 = biasf[colBase + 16 + lrow];
  } else {
    #pragma unroll
    for (int s = 0; s < 4; ++s)
      #pragma unroll
      for (int ct = 0; ct < 2; ++ct){
        int col = ct*16 + lrow;
        bfragP[s][ct] = *(const short8v*)&WT_pos[col*128 + s*32 + lk];
      }
    b0 = bias_pos[lrow]; b1 = bias_pos[16 + lrow];
  }

  for (int tile = blockIdx.x; tile < NTILES; tile += gridDim.x){
    int n0 = tile*64;
    __syncthreads();
    for (int c = tid; c < 64*48; c += 256){
      int row = c / 48, k8 = c % 48;
      int gn = min(n0 + row, N-1);
      const float* src = (k8 < 32) ? &x[(size_t)gn*IN_DIM + k8*8]
                                   : &ev[(size_t)gn*M + (k8-32)*8];
      float4v f0 = *(const float4v*)src;
      float4v f1 = *(const float4v*)(src + 4);
      short8v vv;
      vv[0] = (short)f2bf(f0[0]); vv[1] = (short)f2bf(f0[1]);
      vv[2] = (short)f2bf(f0[2]); vv[3] = (short)f2bf(f0[3]);
      vv[4] = (short)f2bf(f1[0]); vv[5] = (short)f2bf(f1[1]);
      vv[6] = (short)f2bf(f1[2]); vv[7] = (short)f2bf(f1[3]);
      unsigned off = (unsigned)(row*768 + k8*16) ^ (unsigned)((row & 7) << 4);
      *(short8v*)((char*)a_lds + off) = vv;
    }
    __syncthreads();
    float4v acc[4][2];
    #pragma unroll
    for (int nt = 0; nt < 4; ++nt){
      acc[nt][0] = (float4v){0.f,0.f,0.f,0.f};
      acc[nt][1] = (float4v){0.f,0.f,0.f,0.f};
    }
    if (!isPos){
      #pragma unroll
      for (int s = 0; s < 8; ++s)
        #pragma unroll
        for (int nt = 0; nt < 4; ++nt){
          int row = nt*16 + lrow;
          unsigned off = (unsigned)(row*768 + (s*32 + lk)*2) ^ (unsigned)((row & 7) << 4);
          short8v a = *(const short8v*)((const char*)a_lds + off);
          acc[nt][0] = __builtin_amdgcn_mfma_f32_16x16x32_bf16(a, bfragF[s][0], acc[nt][0], 0, 0, 0);
          acc[nt][1] = __builtin_amdgcn_mfma_f32_16x16x32_bf16(a, bfragF[s][1], acc[nt][1], 0, 0, 0);
        }
    } else {
      #pragma unroll
      for (int s = 0; s < 4; ++s)
        #pragma unroll
        for (int nt = 0; nt < 4; ++nt){
          int row = nt*16 + lrow;
          unsigned off = (unsigned)(row*768 + 512 + (s*32 + lk)*2) ^ (unsigned)((row & 7) << 4);
          short8v a = *(const short8v*)((const char*)a_lds + off);
          acc[nt][0] = __builtin_amdgcn_mfma_f32_16x16x32_bf16(a, bfragP[s][0], acc[nt][0], 0, 0, 0);
          acc[nt][1] = __builtin_amdgcn_mfma_f32_16x16x32_bf16(a, bfragP[s][1], acc[nt][1], 0, 0, 0);
        }
    }
    int colBase = isPos ? 96 : wid*32;
    int rbase = (lane >> 4)*4;
    #pragma unroll
    for (int nt = 0; nt < 4; ++nt)
      #pragma unroll
      for (int ct = 0; ct < 2; ++ct){
        int col = colBase + ct*16 + lrow;
        float bb = ct ? b1 : b0;
        #pragma unroll
        for (int r = 0; r < 4; ++r){
          int node = n0 + nt*16 + rbase + r;
          if (node < N) outp[(size_t)node*HID + col] = f2bf(acc[nt][ct][r] + bb);
        }
      }
  }
}

// ---------- gather mean for one LDS row (helper macro-ish via inline) ----------
__device__ __forceinline__ void gather_mean_row(
    const unsigned* __restrict__ hu, const int* __restrict__ row_ptr,
    const unsigned short* __restrict__ csr, int node, int row,
    int grp, int lc, short* a_lds)
{
  int b = row_ptr[node], e = row_ptr[node+1];
  float a0[8] = {0.f,0.f,0.f,0.f,0.f,0.f,0.f,0.f};
  float a1[8] = {0.f,0.f,0.f,0.f,0.f,0.f,0.f,0.f};
  int j = b + grp;
  for (; j + 4 < e; j += 8){
    int s0 = csr[j];
    int s1 = csr[j+4];
    uint4 v0 = *(const uint4*)&hu[(size_t)s0*64 + lc*4];
    uint4 v1 = *(const uint4*)&hu[(size_t)s1*64 + lc*4];
    a0[0] += bf_lo(v0.x); a0[1] += bf_hi(v0.x);
    a0[2] += bf_lo(v0.y); a0[3] += bf_hi(v0.y);
    a0[4] += bf_lo(v0.z); a0[5] += bf_hi(v0.z);
    a0[6] += bf_lo(v0.w); a0[7] += bf_hi(v0.w);
    a1[0] += bf_lo(v1.x); a1[1] += bf_hi(v1.x);
    a1[2] += bf_lo(v1.y); a1[3] += bf_hi(v1.y);
    a1[4] += bf_lo(v1.z); a1[5] += bf_hi(v1.z);
    a1[6] += bf_lo(v1.w); a1[7] += bf_hi(v1.w);
  }
  if (j < e){
    int s0 = csr[j];
    uint4 v0 = *(const uint4*)&hu[(size_t)s0*64 + lc*4];
    a0[0] += bf_lo(v0.x); a0[1] += bf_hi(v0.x);
    a0[2] += bf_lo(v0.y); a0[3] += bf_hi(v0.y);
    a0[4] += bf_lo(v0.z); a0[5] += bf_hi(v0.z);
    a0[6] += bf_lo(v0.w); a0[7] += bf_hi(v0.w);
  }
  #pragma unroll
  for (int k = 0; k < 8; ++k){
    float t = a0[k] + a1[k];
    t += __shfl_xor(t, 16, 64);
    t += __shfl_xor(t, 32, 64);
    a0[k] = t;
  }
  if (grp == 0){
    float inv = 1.0f / fmaxf((float)(e - b), 1.0f);
    short8v mv;
    #pragma unroll
    for (int k = 0; k < 8; ++k) mv[k] = (short)f2bf(a0[k]*inv);
    unsigned off = (unsigned)(row*512 + lc*16) ^ (unsigned)((row & 7) << 4);
    *(short8v*)((char*)a_lds + off) = mv;
  }
}

// ---------- fused agg+conv: relu( mean@Wl.T + bl + h@Wr.T ) -> bf16 ----------
__global__ __launch_bounds__(256) void k_agg_conv(
    const short* __restrict__ hprev, const int* __restrict__ row_ptr,
    const unsigned short* __restrict__ csr,
    const short* __restrict__ WT, const float* __restrict__ bias,
    unsigned short* __restrict__ outp)
{
  __shared__ short a_lds[64*256];   // 32 KiB: cols 0-127 mean, 128-255 h
  const unsigned* hu = (const unsigned*)hprev;
  int tid = threadIdx.x;
  int wid = tid >> 6, lane = tid & 63;
  int colBase = wid*32;
  int lrow = lane & 15, lk = (lane >> 4)*8;
  int grp = lane >> 4, lc = lane & 15;

  short8v bfrag[8][2];
  #pragma unroll
  for (int s = 0; s < 8; ++s)
    #pragma unroll
    for (int ct = 0; ct < 2; ++ct){
      int col = colBase + ct*16 + lrow;
      bfrag[s][ct] = *(const short8v*)&WT[col*256 + s*32 + lk];
    }
  float b0 = bias[colBase + lrow], b1 = bias[colBase + 16 + lrow];

  for (int tile = blockIdx.x; tile < NTILES; tile += gridDim.x){
    int n0 = tile*64;
    __syncthreads();
    // stage h tile -> cols 128..255
    #pragma unroll
    for (int c = tid; c < 64*16; c += 256){
      int row = c >> 4, k8 = c & 15;
      int gn = min(n0 + row, N-1);
      short8v vv = *(const short8v*)(hprev + (size_t)gn*HID + k8*8);
      unsigned off = (unsigned)(row*512 + (16 + k8)*16) ^ (unsigned)((row & 7) << 4);
      *(short8v*)((char*)a_lds + off) = vv;
    }
    // gather means -> cols 0..127 (wave wid owns rows wid*16..wid*16+15)
    for (int r = 0; r < 16; ++r){
      int row = wid*16 + r;
      int node = min(n0 + row, N-1);
      gather_mean_row(hu, row_ptr, csr, node, row, grp, lc, a_lds);
    }
    __syncthreads();
    float4v acc[4][2];
    #pragma unroll
    for (int nt = 0; nt < 4; ++nt){
      acc[nt][0] = (float4v){0.f,0.f,0.f,0.f};
      acc[nt][1] = (float4v){0.f,0.f,0.f,0.f};
    }
    #pragma unroll
    for (int s = 0; s < 8; ++s)
      #pragma unroll
      for (int nt = 0; nt < 4; ++nt){
        int row = nt*16 + lrow;
        unsigned off = (unsigned)(row*512 + (s*32 + lk)*2) ^ (unsigned)((row & 7) << 4);
        short8v a = *(const short8v*)((const char*)a_lds + off);
        acc[nt][0] = __builtin_amdgcn_mfma_f32_16x16x32_bf16(a, bfrag[s][0], acc[nt][0], 0, 0, 0);
        acc[nt][1] = __builtin_amdgcn_mfma_f32_16x16x32_bf16(a, bfrag[s][1], acc[nt][1], 0, 0, 0);
      }
    int rbase = (lane >> 4)*4;
    #pragma unroll
    for (int nt = 0; nt < 4; ++nt)
      #pragma unroll
      for (int ct = 0; ct < 2; ++ct){
        int col = colBase + ct*16 + lrow;
        float bb = ct ? b1 : b0;
        #pragma unroll
        for (int r = 0; r < 4; ++r){
          int node = n0 + nt*16 + rbase + r;
          if (node < N)
            outp[(size_t)node*HID + col] = f2bf(fmaxf(acc[nt][ct][r] + bb, 0.f));
        }
      }
  }
}

// ---------- fused agg+conv2+readout+log_softmax ----------
__global__ __launch_bounds__(256) void k_agg_conv_ro(
    const short* __restrict__ hprev, const int* __restrict__ row_ptr,
    const unsigned short* __restrict__ csr,
    const short* __restrict__ WT, const float* __restrict__ bias,
    const short* __restrict__ WTro, const float* __restrict__ biasro,
    float* __restrict__ out)
{
  __shared__ short a_lds[64*256];   // 32 KiB
  __shared__ short o_lds[64*128];   // 16 KiB relu(conv2) tile
  const unsigned* hu = (const unsigned*)hprev;
  int tid = threadIdx.x;
  int wid = tid >> 6, lane = tid & 63;
  int colBase = wid*32;
  int lrow = lane & 15, lk = (lane >> 4)*8;
  int grp = lane >> 4, lc = lane & 15;

  short8v bfrag[8][2];
  #pragma unroll
  for (int s = 0; s < 8; ++s)
    #pragma unroll
    for (int ct = 0; ct < 2; ++ct){
      int col = colBase + ct*16 + lrow;
      bfrag[s][ct] = *(const short8v*)&WT[col*256 + s*32 + lk];
    }
  float b0 = bias[colBase + lrow], b1 = bias[colBase + 16 + lrow];

  short8v bfragR[4][3];
  #pragma unroll
  for (int s = 0; s < 4; ++s)
    #pragma unroll
    for (int t = 0; t < 3; ++t){
      int col = t*16 + lrow;
      bfragR[s][t] = *(const short8v*)&WTro[col*HID + s*32 + lk];
    }
  float biasR[3] = { biasro[lrow], biasro[16 + lrow], biasro[32 + lrow] };
  bool val2 = lrow < 8;

  for (int tile = blockIdx.x; tile < NTILES; tile += gridDim.x){
    int n0 = tile*64;
    __syncthreads();
    #pragma unroll
    for (int c = tid; c < 64*16; c += 256){
      int row = c >> 4, k8 = c & 15;
      int gn = min(n0 + row, N-1);
      short8v vv = *(const short8v*)(hprev + (size_t)gn*HID + k8*8);
      unsigned off = (unsigned)(row*512 + (16 + k8)*16) ^ (unsigned)((row & 7) << 4);
      *(short8v*)((char*)a_lds + off) = vv;
    }
    for (int r = 0; r < 16; ++r){
      int row = wid*16 + r;
      int node = min(n0 + row, N-1);
      gather_mean_row(hu, row_ptr, csr, node, row, grp, lc, a_lds);
    }
    __syncthreads();
    float4v acc[4][2];
    #pragma unroll
    for (int nt = 0; nt < 4; ++nt){
      acc[nt][0] = (float4v){0.f,0.f,0.f,0.f};
      acc[nt][1] = (float4v){0.f,0.f,0.f,0.f};
    }
    #pragma unroll
    for (int s = 0; s < 8; ++s)
      #pragma unroll
      for (int nt = 0; nt < 4; ++nt){
        int row = nt*16 + lrow;
        unsigned off = (unsigned)(row*512 + (s*32 + lk)*2) ^ (unsigned)((row & 7) << 4);
        short8v a = *(const short8v*)((const char*)a_lds + off);
        acc[nt][0] = __builtin_amdgcn_mfma_f32_16x16x32_bf16(a, bfrag[s][0], acc[nt][0], 0, 0, 0);
        acc[nt][1] = __builtin_amdgcn_mfma_f32_16x16x32_bf16(a, bfrag[s][1], acc[nt][1], 0, 0, 0);
      }
    // relu(conv2) tile -> o_lds (swizzled bf16)
    int rbase = (lane >> 4)*4;
    #pragma unroll
    for (int nt = 0; nt < 4; ++nt)
      #pragma unroll
      for (int ct = 0; ct < 2; ++ct){
        int col = colBase + ct*16 + lrow;
        float bb = ct ? b1 : b0;
        #pragma unroll
        for (int r = 0; r < 4; ++r){
          int row = nt*16 + rbase + r;
          float v = fmaxf(acc[nt][ct][r] + bb, 0.f);
          unsigned off = (unsigned)(row*256 + col*2) ^ (unsigned)((row & 7) << 4);
          *(short*)((char*)o_lds + off) = (short)f2bf(v);
        }
      }
    __syncthreads();
    float4v acc3[3];
    acc3[0] = (float4v){0.f,0.f,0.f,0.f};
    acc3[1] = (float4v){0.f,0.f,0.f,0.f};
    acc3[2] = (float4v){0.f,0.f,0.f,0.f};
    #pragma unroll
    for (int s = 0; s < 4; ++s){
      int row = wid*16 + lrow;
      unsigned off = (unsigned)(row*256 + (s*32 + lk)*2) ^ (unsigned)((row & 7) << 4);
      short8v a = *(const short8v*)((const char*)o_lds + off);
      acc3[0] = __builtin_amdgcn_mfma_f32_16x16x32_bf16(a, bfragR[s][0], acc3[0], 0, 0, 0);
      acc3[1] = __builtin_amdgcn_mfma_f32_16x16x32_bf16(a, bfragR[s][1], acc3[1], 0, 0, 0);
      acc3[2] = __builtin_amdgcn_mfma_f32_16x16x32_bf16(a, bfragR[s][2], acc3[2], 0, 0, 0);
    }
    #pragma unroll
    for (int r = 0; r < 4; ++r){
      float v0 = acc3[0][r] + biasR[0];
      float v1 = acc3[1][r] + biasR[1];
      float v2 = acc3[2][r] + biasR[2];
      float mx = fmaxf(v0, v1);
      mx = fmaxf(mx, val2 ? v2 : -3.4e38f);
      #pragma unroll
      for (int off = 1; off < 16; off <<= 1) mx = fmaxf(mx, __shfl_xor(mx, off, 64));
      float e = expf(v0 - mx) + expf(v1 - mx) + (val2 ? expf(v2 - mx) : 0.f);
      #pragma unroll
      for (int off = 1; off < 16; off <<= 1) e += __shfl_xor(e, off, 64);
      float lz = mx + logf(e);
      int node = n0 + wid*16 + (lane >> 4)*4 + r;
      if (node < N){
        out[(size_t)node*OUT_DIM + lrow]      = v0 - lz;
        out[(size_t)node*OUT_DIM + 16 + lrow] = v1 - lz;
        if (val2) out[(size_t)node*OUT_DIM + 32 + lrow] = v2 - lz;
      }
    }
  }
}

// ---------- bucketed CSR build ----------
__global__ __launch_bounds__(256) void k_hist(const int* __restrict__ dst,
                                              int* __restrict__ bkt_cnt){
  __shared__ int h[NBK];
  int tid = threadIdx.x;
  for (int i = tid; i < NBK; i += 256) h[i] = 0;
  __syncthreads();
  for (int e = blockIdx.x*256 + tid; e < NE; e += gridDim.x*256)
    atomicAdd(&h[dst[e] >> 7], 1);
  __syncthreads();
  for (int i = tid; i < NBK; i += 256){
    int c = h[i];
    if (c) atomicAdd(&bkt_cnt[i], c);
  }
}

__global__ __launch_bounds__(512) void k_bktscan(const int* __restrict__ bkt_cnt,
    int* __restrict__ bkt_start, int* __restrict__ bkt_cursor){
  __shared__ int s[512];
  int t = threadIdx.x;
  int v = (t < NBK) ? bkt_cnt[t] : 0;
  s[t] = v;
  __syncthreads();
  for (int st = 1; st < 512; st <<= 1){
    int a = (t >= st) ? s[t-st] : 0;
    __syncthreads();
    s[t] += a;
    __syncthreads();
  }
  int excl = s[t] - v;
  if (t < NBK){ bkt_start[t] = excl; bkt_cursor[t] = excl; }
  if (t == 0) bkt_start[NBK] = NE;
}

__global__ __launch_bounds__(256) void k_bscatter(const int* __restrict__ src,
    const int* __restrict__ dst, int* __restrict__ bkt_cursor,
    unsigned* __restrict__ estage){
  __shared__ int lcnt[NBK];
  __shared__ int lbase[NBK];
  int tid = threadIdx.x;
  int e0 = blockIdx.x*SREG;
  int e1 = min(e0 + SREG, NE);
  for (int i = tid; i < NBK; i += 256) lcnt[i] = 0;
  __syncthreads();
  for (int e = e0 + tid; e < e1; e += 256)
    atomicAdd(&lcnt[dst[e] >> 7], 1);
  __syncthreads();
  for (int i = tid; i < NBK; i += 256){
    int c = lcnt[i];
    lbase[i] = c ? atomicAdd(&bkt_cursor[i], c) : 0;
    lcnt[i] = 0;
  }
  __syncthreads();
  for (int e = e0 + tid; e < e1; e += 256){
    int d = dst[e];
    int b = d >> 7;
    int slot = lbase[b] + atomicAdd(&lcnt[b], 1);
    estage[slot] = (unsigned)src[e] | ((unsigned)(d & 127) << 16);
  }
}

__global__ __launch_bounds__(256) void k_bcsr(const int* __restrict__ bkt_start,
    const unsigned* __restrict__ estage, unsigned short* __restrict__ csr,
    int* __restrict__ row_ptr){
  __shared__ unsigned eb[BKCAP];
  __shared__ int ncnt[128], sc[128], noff[128];
  int tid = threadIdx.x;
  int b = blockIdx.x;
  int s = bkt_start[b], e = bkt_start[b+1];
  int cnt = min(e - s, BKCAP);
  for (int i = tid; i < cnt; i += 256) eb[i] = estage[s + i];
  if (tid < 128) ncnt[tid] = 0;
  __syncthreads();
  for (int i = tid; i < cnt; i += 256)
    atomicAdd(&ncnt[(eb[i] >> 16) & 127], 1);
  __syncthreads();
  if (tid < 128) sc[tid] = ncnt[tid];
  __syncthreads();
  for (int st = 1; st < 128; st <<= 1){
    int a = (tid < 128 && tid >= st) ? sc[tid-st] : 0;
    __syncthreads();
    if (tid < 128) sc[tid] += a;
    __syncthreads();
  }
  if (tid < 128){
    int excl = sc[tid] - ncnt[tid];
    noff[tid] = excl;
    int node = b*128 + tid;
    if (node <= N) row_ptr[node] = s + excl;
    ncnt[tid] = 0;
  }
  __syncthreads();
  for (int i = tid; i < cnt; i += 256){
    unsigned v = eb[i];
    int ld = (v >> 16) & 127;
    int slot = noff[ld] + atomicAdd(&ncnt[ld], 1);
    csr[s + slot] = (unsigned short)(v & 0xffffu);
  }
}

extern "C" void kernel_launch(void* const* d_in, const int* in_sizes, int n_in,
                              void* d_out, int out_size, void* d_ws, size_t ws_size,
                              hipStream_t stream){
  const float* x     = (const float*)d_in[0];
  const float* ev    = (const float*)d_in[1];
  const float* eigv  = (const float*)d_in[2];
  const int*   ei    = (const int*)d_in[3];
  const float* Wf    = (const float*)d_in[4];
  const float* bf    = (const float*)d_in[5];
  const float* alpha = (const float*)d_in[6];
  const float* Wl1   = (const float*)d_in[7];
  const float* bl1   = (const float*)d_in[8];
  const float* Wr1   = (const float*)d_in[9];
  const float* Wl2   = (const float*)d_in[10];
  const float* bl2   = (const float*)d_in[11];
  const float* Wr2   = (const float*)d_in[12];
  const float* Wro   = (const float*)d_in[13];
  const float* bro   = (const float*)d_in[14];
  float* out = (float*)d_out;

  short* h0b    = (short*)d_ws;            // [N][128] bf16
  short* h1b    = h0b + (size_t)N*HID;
  short* meanb  = h1b + (size_t)N*HID;     // (unused, kept for layout stability)
  short* WTf    = meanb + (size_t)N*HID;   // [128][256]
  short* Wc1    = WTf + 128*256;
  short* Wc2    = Wc1 + 128*256;
  short* WT_pos = Wc2 + 128*256;           // [128][128]
  short* WTro   = WT_pos + 128*128;        // [48][128]
  float* biasf    = (float*)(WTro + 48*128);
  float* bias_pos = biasf + 128;
  float* biasro   = bias_pos + 128;
  unsigned* encmn = (unsigned*)(biasro + 48);
  unsigned* encmx = encmn + M;
  int* bkt_cnt    = (int*)(encmx + M);     // [391]
  int* bkt_start  = bkt_cnt + NBK;         // [392]
  int* bkt_cursor = bkt_start + NBK + 1;   // [391]
  int* row_ptr    = bkt_cursor + NBK;      // [N+1]
  unsigned* estage = (unsigned*)(row_ptr + N + 1);      // [NE]
  unsigned short* csr = (unsigned short*)(estage + NE); // [NE]
  float* pe_raw = (float*)(csr + NE);      // [128][32]

  const int* srcA = ei;
  const int* dstA = ei + NE;

  k_init<<<NSCAN, 256, 0, stream>>>(encmn, encmx, WT_pos, bias_pos, bkt_cnt);
  k_colminmax<<<256, 256, 0, stream>>>(ev, encmn, encmx);
  k_pe<<<16, 256, 0, stream>>>(eigv, alpha, encmn, encmx,
                               Wf, bf, Wl1, Wr1, Wl2, Wr2, Wro, bro,
                               WT_pos, pe_raw, out + (size_t)N*OUT_DIM,
                               WTf, biasf, Wc1, Wc2, WTro, biasro);
  k_bias<<<1, 256, 0, stream>>>(encmn, encmx, pe_raw, bias_pos);
  // CSR build (bucketed, write-merged)
  k_hist<<<512, 256, 0, stream>>>(dstA, bkt_cnt);
  k_bktscan<<<1, 512, 0, stream>>>(bkt_cnt, bkt_start, bkt_cursor);
  k_bscatter<<<NSCATB, 256, 0, stream>>>(srcA, dstA, bkt_cursor, estage);
  k_bcsr<<<NBK, 256, 0, stream>>>(bkt_start, estage, csr, row_ptr);
  // dense pipeline (agg fused into convs; meanb eliminated)
  k_gemm_in<<<NTILES, 256, 0, stream>>>(x, ev, WTf, biasf, WT_pos, bias_pos,
                                        (unsigned short*)h0b);
  k_agg_conv<<<NTILES, 256, 0, stream>>>(h0b, row_ptr, csr, Wc1, bl1,
                                         (unsigned short*)h1b);
  k_agg_conv_ro<<<NTILES, 256, 0, stream>>>(h1b, row_ptr, csr, Wc2, bl2,
                                            WTro, biasro, out);
}

// Round 11
// 210.875 us; speedup vs baseline: 1.7656x; 1.7656x over previous
//
#include <hip/hip_runtime.h>
#include <math.h>

#define N        50000
#define IN_DIM   256
#define H_DIM    96
#define POS_DIM  32
#define KCH      64
#define M        128
#define NE       800000
#define OUT_DIM  40
#define HID      128
#define NSCAN    196             // ceil(N/256)
#define NTILES   ((N + 63) / 64) // 782
#define NBK      391             // ceil(N/128) buckets of 128 nodes
#define BKCAP    2560            // bucket edge cap
#define NSCATB   512             // bscatter blocks
#define SREG     1563            // edges per bscatter block

typedef __attribute__((ext_vector_type(8))) short short8v;
typedef __attribute__((ext_vector_type(4))) float float4v;

// ---------- bf16 helpers ----------
__device__ __forceinline__ unsigned short f2bf(float f){
  unsigned u = __float_as_uint(f);
  u += 0x7fffu + ((u >> 16) & 1u);      // RNE
  return (unsigned short)(u >> 16);
}
__device__ __forceinline__ float bf_lo(unsigned u){ return __uint_as_float(u << 16); }
__device__ __forceinline__ float bf_hi(unsigned u){ return __uint_as_float(u & 0xffff0000u); }

// ---------- float <-> ordered-uint encoding for atomic min/max ----------
__device__ __forceinline__ unsigned enc_key(float f){
  unsigned u = __float_as_uint(f);
  return (u & 0x80000000u) ? ~u : (u | 0x80000000u);
}
__device__ __forceinline__ float dec_key(unsigned k){
  unsigned u = (k & 0x80000000u) ? (k ^ 0x80000000u) : ~k;
  return __uint_as_float(u);
}

// ---------- init ----------
__global__ void k_init(unsigned* __restrict__ encmn, unsigned* __restrict__ encmx,
                       short* __restrict__ WT_pos, int* __restrict__ bkt_cnt){
  int i = blockIdx.x*blockDim.x + threadIdx.x;
  if (i < M){ encmn[i] = 0xFFFFFFFFu; encmx[i] = 0u; }
  if (i < M*M) WT_pos[i] = 0;
  if (i < NBK) bkt_cnt[i] = 0;
}

// ---------- fused: colminmax (blocks 0..255) | hist (blocks 256..767) ----------
__global__ __launch_bounds__(256) void k_f1(const float* __restrict__ ev,
    unsigned* __restrict__ encmn, unsigned* __restrict__ encmx,
    const int* __restrict__ dst, int* __restrict__ bkt_cnt){
  int tid = threadIdx.x;
  if (blockIdx.x < 256){
    __shared__ float4 smn[256], smx[256];
    int cg  = tid & 31;
    int rs  = blockIdx.x*8 + (tid >> 5);
    float4 mn = make_float4( 3.4e38f,  3.4e38f,  3.4e38f,  3.4e38f);
    float4 mx = make_float4(-3.4e38f, -3.4e38f, -3.4e38f, -3.4e38f);
    #pragma unroll 4
    for (int r = rs; r < N; r += 2048){
      float4 v = *(const float4*)&ev[(size_t)r*M + cg*4];
      mn.x = fminf(mn.x, v.x); mn.y = fminf(mn.y, v.y);
      mn.z = fminf(mn.z, v.z); mn.w = fminf(mn.w, v.w);
      mx.x = fmaxf(mx.x, v.x); mx.y = fmaxf(mx.y, v.y);
      mx.z = fmaxf(mx.z, v.z); mx.w = fmaxf(mx.w, v.w);
    }
    smn[tid] = mn; smx[tid] = mx;
    __syncthreads();
    for (int s = 128; s >= 32; s >>= 1){
      if (tid < s){
        float4 a = smn[tid], b = smn[tid + s];
        smn[tid] = make_float4(fminf(a.x,b.x), fminf(a.y,b.y), fminf(a.z,b.z), fminf(a.w,b.w));
        float4 c = smx[tid], d = smx[tid + s];
        smx[tid] = make_float4(fmaxf(c.x,d.x), fmaxf(c.y,d.y), fmaxf(c.z,d.z), fmaxf(c.w,d.w));
      }
      __syncthreads();
    }
    if (tid < 32){
      float4 a = smn[tid], b = smx[tid];
      atomicMin(&encmn[tid*4+0], enc_key(a.x));
      atomicMin(&encmn[tid*4+1], enc_key(a.y));
      atomicMin(&encmn[tid*4+2], enc_key(a.z));
      atomicMin(&encmn[tid*4+3], enc_key(a.w));
      atomicMax(&encmx[tid*4+0], enc_key(b.x));
      atomicMax(&encmx[tid*4+1], enc_key(b.y));
      atomicMax(&encmx[tid*4+2], enc_key(b.z));
      atomicMax(&encmx[tid*4+3], enc_key(b.w));
    }
  } else {
    __shared__ int hh[NBK];
    int bid = blockIdx.x - 256;   // 0..511
    for (int i = tid; i < NBK; i += 256) hh[i] = 0;
    __syncthreads();
    for (int e = bid*256 + tid; e < NE; e += 512*256)
      atomicAdd(&hh[dst[e] >> 7], 1);
    __syncthreads();
    for (int i = tid; i < NBK; i += 256){
      int c = hh[i];
      if (c) atomicAdd(&bkt_cnt[i], c);
    }
  }
}

// ---------- fused: PE+weight-prep (blocks 0..7) | bktscan (block 8); 512 thr ----------
__global__ __launch_bounds__(512) void k_f2(
    const float* __restrict__ eigval, const float* __restrict__ alpha,
    const unsigned* __restrict__ encmn, const unsigned* __restrict__ encmx,
    const float* __restrict__ Wf, const float* __restrict__ bfeat,
    const float* __restrict__ Wl1, const float* __restrict__ Wr1,
    const float* __restrict__ Wl2, const float* __restrict__ Wr2,
    const float* __restrict__ Wro, const float* __restrict__ bro,
    short* __restrict__ WT_pos, float* __restrict__ pe_raw, float* __restrict__ pe_out,
    short* __restrict__ WTf, float* __restrict__ biasf,
    short* __restrict__ Wc1, short* __restrict__ Wc2,
    short* __restrict__ WTro, float* __restrict__ biasro,
    const int* __restrict__ bkt_cnt, int* __restrict__ bkt_start,
    int* __restrict__ bkt_cursor){
  int tid = threadIdx.x;
  if (blockIdx.x < 8){
    __shared__ float rmn[128], rmx[128];
    if (tid < 128){ float v = eigval[tid]; rmn[tid] = v; rmx[tid] = v; }
    __syncthreads();
    for (int s = 64; s; s >>= 1){
      if (tid < s){ rmn[tid] = fminf(rmn[tid], rmn[tid+s]); rmx[tid] = fmaxf(rmx[tid], rmx[tid+s]); }
      __syncthreads();
    }
    float lmin = rmn[0], lmax = rmx[0];
    int g = blockIdx.x*512 + tid;   // 0..4095
    int m = g >> 5, p = g & 31;
    float v = eigval[m];
    float lam = (v - lmin)/(lmax - lmin)*2.0f - 1.0f;
    lam = fminf(1.0f, fmaxf(-1.0f, lam));
    float t0 = 1.0f, t1 = lam;
    float acc = alpha[p] + lam*alpha[POS_DIM + p];
    float two_lam = lam + lam;
    #pragma unroll
    for (int k = 2; k < KCH; ++k){
      float t2 = fmaf(two_lam, t1, -t0);
      acc = fmaf(t2, alpha[k*POS_DIM + p], acc);
      t0 = t1; t1 = t2;
    }
    pe_out[g] = acc;
    pe_raw[g] = acc;
    float cmn = dec_key(encmn[m]);
    float cmx = dec_key(encmx[m]);
    float A = 2.0f/(cmx - cmn);
    WT_pos[p*M + m] = (short)f2bf(A*acc);
    for (int i = g; i < 128*256; i += 4096){
      int c = i >> 8, k = i & 255;
      WTf[i] = (c < H_DIM) ? (short)f2bf(Wf[c*IN_DIM + k]) : (short)0;
      Wc1[i] = (short)f2bf((k < HID) ? Wl1[c*HID + k] : Wr1[c*HID + k - HID]);
      Wc2[i] = (short)f2bf((k < HID) ? Wl2[c*HID + k] : Wr2[c*HID + k - HID]);
    }
    for (int i = g; i < 48*128; i += 4096){
      int c = i >> 7, k = i & 127;
      WTro[i] = (c < OUT_DIM) ? (short)f2bf(Wro[c*HID + k]) : (short)0;
    }
    if (g < 128) biasf[g] = (g < H_DIM) ? bfeat[g] : 0.f;
    if (g >= 128 && g < 176) biasro[g - 128] = (g - 128 < OUT_DIM) ? bro[g - 128] : 0.f;
  } else {
    __shared__ int s[512];
    int t = tid;
    int v = (t < NBK) ? bkt_cnt[t] : 0;
    s[t] = v;
    __syncthreads();
    for (int st = 1; st < 512; st <<= 1){
      int a = (t >= st) ? s[t-st] : 0;
      __syncthreads();
      s[t] += a;
      __syncthreads();
    }
    int excl = s[t] - v;
    if (t < NBK){ bkt_start[t] = excl; bkt_cursor[t] = excl; }
    if (t == 0) bkt_start[NBK] = NE;
  }
}

// ---------- fused: bscatter (blocks 0..511) | bias fold (block 512) ----------
__global__ __launch_bounds__(256) void k_f3(const int* __restrict__ src,
    const int* __restrict__ dst, int* __restrict__ bkt_cursor,
    unsigned* __restrict__ estage,
    const unsigned* __restrict__ encmn, const unsigned* __restrict__ encmx,
    const float* __restrict__ pe_raw, float* __restrict__ bias_pos){
  int tid = threadIdx.x;
  if (blockIdx.x < NSCATB){
    __shared__ int lcnt[NBK];
    __shared__ int lbase[NBK];
    int e0 = blockIdx.x*SREG;
    int e1 = min(e0 + SREG, NE);
    for (int i = tid; i < NBK; i += 256) lcnt[i] = 0;
    __syncthreads();
    for (int e = e0 + tid; e < e1; e += 256)
      atomicAdd(&lcnt[dst[e] >> 7], 1);
    __syncthreads();
    for (int i = tid; i < NBK; i += 256){
      int c = lcnt[i];
      lbase[i] = c ? atomicAdd(&bkt_cursor[i], c) : 0;
      lcnt[i] = 0;
    }
    __syncthreads();
    for (int e = e0 + tid; e < e1; e += 256){
      int d = dst[e];
      int b = d >> 7;
      int slot = lbase[b] + atomicAdd(&lcnt[b], 1);
      estage[slot] = (unsigned)src[e] | ((unsigned)(d & 127) << 16);
    }
  } else {
    __shared__ float s[256];
    int p = tid >> 3, c = tid & 7;
    float sum = 0.f;
    for (int m = c*16; m < c*16 + 16; ++m){
      float cmn = dec_key(encmn[m]);
      float cmx = dec_key(encmx[m]);
      float A = 2.0f/(cmx - cmn);
      float B = -cmn*A - 1.0f;
      sum += B*pe_raw[m*POS_DIM + p];
    }
    s[tid] = sum;
    __syncthreads();
    if (c == 0){
      float t = 0.f;
      #pragma unroll
      for (int j = 0; j < 8; ++j) t += s[p*8 + j];
      bias_pos[p] = t;
    }
  }
}

// ---------- fused: bcsr (blocks 0..390) | input GEMM (blocks 391..1172) ----------
__global__ __launch_bounds__(256) void k_f4(
    const int* __restrict__ bkt_start, const unsigned* __restrict__ estage,
    unsigned short* __restrict__ csr, int* __restrict__ row_ptr,
    const float* __restrict__ x, const float* __restrict__ ev,
    const short* __restrict__ WTf, const float* __restrict__ biasf,
    const short* __restrict__ WT_pos, const float* __restrict__ bias_pos,
    unsigned short* __restrict__ outp)
{
  __shared__ __align__(16) char smem[64*384*2];   // 48 KiB overlay
  int tid = threadIdx.x;
  if (blockIdx.x < NBK){
    unsigned* eb = (unsigned*)smem;                 // [BKCAP]
    int* ncnt = (int*)(smem + BKCAP*4);
    int* sc   = ncnt + 128;
    int* noff = sc + 128;
    int b = blockIdx.x;
    int s = bkt_start[b], e = bkt_start[b+1];
    int cnt = min(e - s, BKCAP);
    for (int i = tid; i < cnt; i += 256) eb[i] = estage[s + i];
    if (tid < 128) ncnt[tid] = 0;
    __syncthreads();
    for (int i = tid; i < cnt; i += 256)
      atomicAdd(&ncnt[(eb[i] >> 16) & 127], 1);
    __syncthreads();
    if (tid < 128) sc[tid] = ncnt[tid];
    __syncthreads();
    for (int st = 1; st < 128; st <<= 1){
      int a = (tid < 128 && tid >= st) ? sc[tid-st] : 0;
      __syncthreads();
      if (tid < 128) sc[tid] += a;
      __syncthreads();
    }
    if (tid < 128){
      int excl = sc[tid] - ncnt[tid];
      noff[tid] = excl;
      int node = b*128 + tid;
      if (node <= N) row_ptr[node] = s + excl;
      ncnt[tid] = 0;
    }
    __syncthreads();
    for (int i = tid; i < cnt; i += 256){
      unsigned v = eb[i];
      int ld = (v >> 16) & 127;
      int slot = noff[ld] + atomicAdd(&ncnt[ld], 1);
      csr[s + slot] = (unsigned short)(v & 0xffffu);
    }
    return;
  }
  // ---- input GEMM part ----
  short* a_lds = (short*)smem;   // [64*384]
  int wid = tid >> 6, lane = tid & 63;
  int lrow = lane & 15, lk = (lane >> 4)*8;
  bool isPos = (wid == 3);

  short8v bfragF[8][2];
  short8v bfragP[4][2];
  float b0, b1;
  if (!isPos){
    int colBase = wid*32;
    #pragma unroll
    for (int s = 0; s < 8; ++s)
      #pragma unroll
      for (int ct = 0; ct < 2; ++ct){
        int col = colBase + ct*16 + lrow;
        bfragF[s][ct] = *(const short8v*)&WTf[col*256 + s*32 + lk];
      }
    b0 = biasf[colBase + lrow]; b1 = biasf[colBase + 16 + lrow];
  } else {
    #pragma unroll
    for (int s = 0; s < 4; ++s)
      #pragma unroll
      for (int ct = 0; ct < 2; ++ct){
        int col = ct*16 + lrow;
        bfragP[s][ct] = *(const short8v*)&WT_pos[col*128 + s*32 + lk];
      }
    b0 = bias_pos[lrow]; b1 = bias_pos[16 + lrow];
  }

  for (int tile = blockIdx.x - NBK; tile < NTILES; tile += gridDim.x - NBK){
    int n0 = tile*64;
    __syncthreads();
    for (int c = tid; c < 64*48; c += 256){
      int row = c / 48, k8 = c % 48;
      int gn = min(n0 + row, N-1);
      const float* src = (k8 < 32) ? &x[(size_t)gn*IN_DIM + k8*8]
                                   : &ev[(size_t)gn*M + (k8-32)*8];
      float4v f0 = *(const float4v*)src;
      float4v f1 = *(const float4v*)(src + 4);
      short8v vv;
      vv[0] = (short)f2bf(f0[0]); vv[1] = (short)f2bf(f0[1]);
      vv[2] = (short)f2bf(f0[2]); vv[3] = (short)f2bf(f0[3]);
      vv[4] = (short)f2bf(f1[0]); vv[5] = (short)f2bf(f1[1]);
      vv[6] = (short)f2bf(f1[2]); vv[7] = (short)f2bf(f1[3]);
      unsigned off = (unsigned)(row*768 + k8*16) ^ (unsigned)((row & 7) << 4);
      *(short8v*)((char*)a_lds + off) = vv;
    }
    __syncthreads();
    float4v acc[4][2];
    #pragma unroll
    for (int nt = 0; nt < 4; ++nt){
      acc[nt][0] = (float4v){0.f,0.f,0.f,0.f};
      acc[nt][1] = (float4v){0.f,0.f,0.f,0.f};
    }
    if (!isPos){
      #pragma unroll
      for (int s = 0; s < 8; ++s)
        #pragma unroll
        for (int nt = 0; nt < 4; ++nt){
          int row = nt*16 + lrow;
          unsigned off = (unsigned)(row*768 + (s*32 + lk)*2) ^ (unsigned)((row & 7) << 4);
          short8v a = *(const short8v*)((const char*)a_lds + off);
          acc[nt][0] = __builtin_amdgcn_mfma_f32_16x16x32_bf16(a, bfragF[s][0], acc[nt][0], 0, 0, 0);
          acc[nt][1] = __builtin_amdgcn_mfma_f32_16x16x32_bf16(a, bfragF[s][1], acc[nt][1], 0, 0, 0);
        }
    } else {
      #pragma unroll
      for (int s = 0; s < 4; ++s)
        #pragma unroll
        for (int nt = 0; nt < 4; ++nt){
          int row = nt*16 + lrow;
          unsigned off = (unsigned)(row*768 + 512 + (s*32 + lk)*2) ^ (unsigned)((row & 7) << 4);
          short8v a = *(const short8v*)((const char*)a_lds + off);
          acc[nt][0] = __builtin_amdgcn_mfma_f32_16x16x32_bf16(a, bfragP[s][0], acc[nt][0], 0, 0, 0);
          acc[nt][1] = __builtin_amdgcn_mfma_f32_16x16x32_bf16(a, bfragP[s][1], acc[nt][1], 0, 0, 0);
        }
    }
    int colBase = isPos ? 96 : wid*32;
    int rbase = (lane >> 4)*4;
    #pragma unroll
    for (int nt = 0; nt < 4; ++nt)
      #pragma unroll
      for (int ct = 0; ct < 2; ++ct){
        int col = colBase + ct*16 + lrow;
        float bb = ct ? b1 : b0;
        #pragma unroll
        for (int r = 0; r < 4; ++r){
          int node = n0 + nt*16 + rbase + r;
          if (node < N) outp[(size_t)node*HID + col] = f2bf(acc[nt][ct][r] + bb);
        }
      }
  }
}

// ---------- mean aggregation: one wave per node, 16 edges in flight ----------
__global__ __launch_bounds__(256) void k_agg_b(const unsigned* __restrict__ h,
    const int* __restrict__ row_ptr, const unsigned short* __restrict__ csr,
    unsigned* __restrict__ outm){
  int gid = blockIdx.x*blockDim.x + threadIdx.x;
  int i = gid >> 6;
  int lane = gid & 63;
  if (i >= N) return;
  int grp = lane >> 4;
  int lc  = lane & 15;
  int b = row_ptr[i], e = row_ptr[i+1];
  float a0[8] = {0,0,0,0,0,0,0,0}, a1[8] = {0,0,0,0,0,0,0,0};
  float a2[8] = {0,0,0,0,0,0,0,0}, a3[8] = {0,0,0,0,0,0,0,0};
  int j = b + grp;
  for (; j + 12 < e; j += 16){
    uint4 v0 = *(const uint4*)&h[(size_t)csr[j]*64    + lc*4];
    uint4 v1 = *(const uint4*)&h[(size_t)csr[j+4]*64  + lc*4];
    uint4 v2 = *(const uint4*)&h[(size_t)csr[j+8]*64  + lc*4];
    uint4 v3 = *(const uint4*)&h[(size_t)csr[j+12]*64 + lc*4];
    a0[0] += bf_lo(v0.x); a0[1] += bf_hi(v0.x); a0[2] += bf_lo(v0.y); a0[3] += bf_hi(v0.y);
    a0[4] += bf_lo(v0.z); a0[5] += bf_hi(v0.z); a0[6] += bf_lo(v0.w); a0[7] += bf_hi(v0.w);
    a1[0] += bf_lo(v1.x); a1[1] += bf_hi(v1.x); a1[2] += bf_lo(v1.y); a1[3] += bf_hi(v1.y);
    a1[4] += bf_lo(v1.z); a1[5] += bf_hi(v1.z); a1[6] += bf_lo(v1.w); a1[7] += bf_hi(v1.w);
    a2[0] += bf_lo(v2.x); a2[1] += bf_hi(v2.x); a2[2] += bf_lo(v2.y); a2[3] += bf_hi(v2.y);
    a2[4] += bf_lo(v2.z); a2[5] += bf_hi(v2.z); a2[6] += bf_lo(v2.w); a2[7] += bf_hi(v2.w);
    a3[0] += bf_lo(v3.x); a3[1] += bf_hi(v3.x); a3[2] += bf_lo(v3.y); a3[3] += bf_hi(v3.y);
    a3[4] += bf_lo(v3.z); a3[5] += bf_hi(v3.z); a3[6] += bf_lo(v3.w); a3[7] += bf_hi(v3.w);
  }
  for (; j < e; j += 4){
    uint4 v0 = *(const uint4*)&h[(size_t)csr[j]*64 + lc*4];
    a0[0] += bf_lo(v0.x); a0[1] += bf_hi(v0.x); a0[2] += bf_lo(v0.y); a0[3] += bf_hi(v0.y);
    a0[4] += bf_lo(v0.z); a0[5] += bf_hi(v0.z); a0[6] += bf_lo(v0.w); a0[7] += bf_hi(v0.w);
  }
  #pragma unroll
  for (int k = 0; k < 8; ++k){
    float t = (a0[k] + a1[k]) + (a2[k] + a3[k]);
    t += __shfl_xor(t, 16, 64);
    t += __shfl_xor(t, 32, 64);
    a0[k] = t;
  }
  if (grp == 0){
    float inv = 1.0f / fmaxf((float)(e - b), 1.0f);
    uint4 o;
    o.x = (unsigned)f2bf(a0[0]*inv) | ((unsigned)f2bf(a0[1]*inv) << 16);
    o.y = (unsigned)f2bf(a0[2]*inv) | ((unsigned)f2bf(a0[3]*inv) << 16);
    o.z = (unsigned)f2bf(a0[4]*inv) | ((unsigned)f2bf(a0[5]*inv) << 16);
    o.w = (unsigned)f2bf(a0[6]*inv) | ((unsigned)f2bf(a0[7]*inv) << 16);
    *(uint4*)&outm[(size_t)i*64 + lc*4] = o;
  }
}

// ---------- conv1 GEMM (TWOSRC): relu(mean@Wl.T + bl + h@Wr.T) -> bf16 ----------
__global__ __launch_bounds__(256) void k_conv(
    const short* __restrict__ A0, const short* __restrict__ A1,
    const short* __restrict__ WT, const float* __restrict__ bias,
    unsigned short* __restrict__ outp)
{
  __shared__ short a_lds[64*256];
  int tid = threadIdx.x;
  int wid = tid >> 6, lane = tid & 63;
  int colBase = wid*32;
  int lrow = lane & 15, lk = (lane >> 4)*8;

  short8v bfrag[8][2];
  #pragma unroll
  for (int s = 0; s < 8; ++s)
    #pragma unroll
    for (int ct = 0; ct < 2; ++ct){
      int col = colBase + ct*16 + lrow;
      bfrag[s][ct] = *(const short8v*)&WT[col*256 + s*32 + lk];
    }
  float b0 = bias[colBase + lrow], b1 = bias[colBase + 16 + lrow];

  for (int tile = blockIdx.x; tile < NTILES; tile += gridDim.x){
    int n0 = tile*64;
    __syncthreads();
    #pragma unroll
    for (int c = tid; c < 64*32; c += 256){
      int row = c >> 5, k8 = c & 31;
      int gn = min(n0 + row, N-1);
      const short* src = (k8 < 16) ? (A0 + (size_t)gn*HID + k8*8)
                                   : (A1 + (size_t)gn*HID + (k8-16)*8);
      short8v vv = *(const short8v*)src;
      unsigned off = (unsigned)(row*512 + k8*16) ^ (unsigned)((row & 7) << 4);
      *(short8v*)((char*)a_lds + off) = vv;
    }
    __syncthreads();
    float4v acc[4][2];
    #pragma unroll
    for (int nt = 0; nt < 4; ++nt){
      acc[nt][0] = (float4v){0.f,0.f,0.f,0.f};
      acc[nt][1] = (float4v){0.f,0.f,0.f,0.f};
    }
    #pragma unroll
    for (int s = 0; s < 8; ++s)
      #pragma unroll
      for (int nt = 0; nt < 4; ++nt){
        int row = nt*16 + lrow;
        unsigned off = (unsigned)(row*512 + (s*32 + lk)*2) ^ (unsigned)((row & 7) << 4);
        short8v a = *(const short8v*)((const char*)a_lds + off);
        acc[nt][0] = __builtin_amdgcn_mfma_f32_16x16x32_bf16(a, bfrag[s][0], acc[nt][0], 0, 0, 0);
        acc[nt][1] = __builtin_amdgcn_mfma_f32_16x16x32_bf16(a, bfrag[s][1], acc[nt][1], 0, 0, 0);
      }
    int rbase = (lane >> 4)*4;
    #pragma unroll
    for (int nt = 0; nt < 4; ++nt)
      #pragma unroll
      for (int ct = 0; ct < 2; ++ct){
        int col = colBase + ct*16 + lrow;
        float bb = ct ? b1 : b0;
        #pragma unroll
        for (int r = 0; r < 4; ++r){
          int node = n0 + nt*16 + rbase + r;
          if (node < N)
            outp[(size_t)node*HID + col] = f2bf(fmaxf(acc[nt][ct][r] + bb, 0.f));
        }
      }
  }
}

// ---------- conv2 fused with readout + log_softmax ----------
__global__ __launch_bounds__(256) void k_conv_ro(
    const short* __restrict__ A0, const short* __restrict__ A1,
    const short* __restrict__ WT, const float* __restrict__ bias,
    const short* __restrict__ WTro, const float* __restrict__ biasro,
    float* __restrict__ out)
{
  __shared__ short a_lds[64*256];
  __shared__ short o_lds[64*128];
  int tid = threadIdx.x;
  int wid = tid >> 6, lane = tid & 63;
  int colBase = wid*32;
  int lrow = lane & 15, lk = (lane >> 4)*8;

  short8v bfrag[8][2];
  #pragma unroll
  for (int s = 0; s < 8; ++s)
    #pragma unroll
    for (int ct = 0; ct < 2; ++ct){
      int col = colBase + ct*16 + lrow;
      bfrag[s][ct] = *(const short8v*)&WT[col*256 + s*32 + lk];
    }
  float b0 = bias[colBase + lrow], b1 = bias[colBase + 16 + lrow];

  short8v bfragR[4][3];
  #pragma unroll
  for (int s = 0; s < 4; ++s)
    #pragma unroll
    for (int t = 0; t < 3; ++t){
      int col = t*16 + lrow;
      bfragR[s][t] = *(const short8v*)&WTro[col*HID + s*32 + lk];
    }
  float biasR[3] = { biasro[lrow], biasro[16 + lrow], biasro[32 + lrow] };
  bool val2 = lrow < 8;

  for (int tile = blockIdx.x; tile < NTILES; tile += gridDim.x){
    int n0 = tile*64;
    __syncthreads();
    #pragma unroll
    for (int c = tid; c < 64*32; c += 256){
      int row = c >> 5, k8 = c & 31;
      int gn = min(n0 + row, N-1);
      const short* src = (k8 < 16) ? (A0 + (size_t)gn*HID + k8*8)
                                   : (A1 + (size_t)gn*HID + (k8-16)*8);
      short8v vv = *(const short8v*)src;
      unsigned off = (unsigned)(row*512 + k8*16) ^ (unsigned)((row & 7) << 4);
      *(short8v*)((char*)a_lds + off) = vv;
    }
    __syncthreads();
    float4v acc[4][2];
    #pragma unroll
    for (int nt = 0; nt < 4; ++nt){
      acc[nt][0] = (float4v){0.f,0.f,0.f,0.f};
      acc[nt][1] = (float4v){0.f,0.f,0.f,0.f};
    }
    #pragma unroll
    for (int s = 0; s < 8; ++s)
      #pragma unroll
      for (int nt = 0; nt < 4; ++nt){
        int row = nt*16 + lrow;
        unsigned off = (unsigned)(row*512 + (s*32 + lk)*2) ^ (unsigned)((row & 7) << 4);
        short8v a = *(const short8v*)((const char*)a_lds + off);
        acc[nt][0] = __builtin_amdgcn_mfma_f32_16x16x32_bf16(a, bfrag[s][0], acc[nt][0], 0, 0, 0);
        acc[nt][1] = __builtin_amdgcn_mfma_f32_16x16x32_bf16(a, bfrag[s][1], acc[nt][1], 0, 0, 0);
      }
    int rbase = (lane >> 4)*4;
    #pragma unroll
    for (int nt = 0; nt < 4; ++nt)
      #pragma unroll
      for (int ct = 0; ct < 2; ++ct){
        int col = colBase + ct*16 + lrow;
        float bb = ct ? b1 : b0;
        #pragma unroll
        for (int r = 0; r < 4; ++r){
          int row = nt*16 + rbase + r;
          float v = fmaxf(acc[nt][ct][r] + bb, 0.f);
          unsigned off = (unsigned)(row*256 + col*2) ^ (unsigned)((row & 7) << 4);
          *(short*)((char*)o_lds + off) = (short)f2bf(v);
        }
      }
    __syncthreads();
    float4v acc3[3];
    acc3[0] = (float4v){0.f,0.f,0.f,0.f};
    acc3[1] = (float4v){0.f,0.f,0.f,0.f};
    acc3[2] = (float4v){0.f,0.f,0.f,0.f};
    #pragma unroll
    for (int s = 0; s < 4; ++s){
      int row = wid*16 + lrow;
      unsigned off = (unsigned)(row*256 + (s*32 + lk)*2) ^ (unsigned)((row & 7) << 4);
      short8v a = *(const short8v*)((const char*)o_lds + off);
      acc3[0] = __builtin_amdgcn_mfma_f32_16x16x32_bf16(a, bfragR[s][0], acc3[0], 0, 0, 0);
      acc3[1] = __builtin_amdgcn_mfma_f32_16x16x32_bf16(a, bfragR[s][1], acc3[1], 0, 0, 0);
      acc3[2] = __builtin_amdgcn_mfma_f32_16x16x32_bf16(a, bfragR[s][2], acc3[2], 0, 0, 0);
    }
    #pragma unroll
    for (int r = 0; r < 4; ++r){
      float v0 = acc3[0][r] + biasR[0];
      float v1 = acc3[1][r] + biasR[1];
      float v2 = acc3[2][r] + biasR[2];
      float mx = fmaxf(v0, v1);
      mx = fmaxf(mx, val2 ? v2 : -3.4e38f);
      #pragma unroll
      for (int off = 1; off < 16; off <<= 1) mx = fmaxf(mx, __shfl_xor(mx, off, 64));
      float e = expf(v0 - mx) + expf(v1 - mx) + (val2 ? expf(v2 - mx) : 0.f);
      #pragma unroll
      for (int off = 1; off < 16; off <<= 1) e += __shfl_xor(e, off, 64);
      float lz = mx + logf(e);
      int node = n0 + wid*16 + (lane >> 4)*4 + r;
      if (node < N){
        out[(size_t)node*OUT_DIM + lrow]      = v0 - lz;
        out[(size_t)node*OUT_DIM + 16 + lrow] = v1 - lz;
        if (val2) out[(size_t)node*OUT_DIM + 32 + lrow] = v2 - lz;
      }
    }
  }
}

extern "C" void kernel_launch(void* const* d_in, const int* in_sizes, int n_in,
                              void* d_out, int out_size, void* d_ws, size_t ws_size,
                              hipStream_t stream){
  const float* x     = (const float*)d_in[0];
  const float* ev    = (const float*)d_in[1];
  const float* eigv  = (const float*)d_in[2];
  const int*   ei    = (const int*)d_in[3];
  const float* Wf    = (const float*)d_in[4];
  const float* bf    = (const float*)d_in[5];
  const float* alpha = (const float*)d_in[6];
  const float* Wl1   = (const float*)d_in[7];
  const float* bl1   = (const float*)d_in[8];
  const float* Wr1   = (const float*)d_in[9];
  const float* Wl2   = (const float*)d_in[10];
  const float* bl2   = (const float*)d_in[11];
  const float* Wr2   = (const float*)d_in[12];
  const float* Wro   = (const float*)d_in[13];
  const float* bro   = (const float*)d_in[14];
  float* out = (float*)d_out;

  short* h0b    = (short*)d_ws;            // [N][128] bf16
  short* h1b    = h0b + (size_t)N*HID;
  short* meanb  = h1b + (size_t)N*HID;
  short* WTf    = meanb + (size_t)N*HID;   // [128][256]
  short* Wc1    = WTf + 128*256;
  short* Wc2    = Wc1 + 128*256;
  short* WT_pos = Wc2 + 128*256;           // [128][128]
  short* WTro   = WT_pos + 128*128;        // [48][128]
  float* biasf    = (float*)(WTro + 48*128);
  float* bias_pos = biasf + 128;
  float* biasro   = bias_pos + 128;
  unsigned* encmn = (unsigned*)(biasro + 48);
  unsigned* encmx = encmn + M;
  int* bkt_cnt    = (int*)(encmx + M);     // [391]
  int* bkt_start  = bkt_cnt + NBK;         // [392]
  int* bkt_cursor = bkt_start + NBK + 1;   // [391]
  int* row_ptr    = bkt_cursor + NBK;      // [N+1]
  unsigned* estage = (unsigned*)(row_ptr + N + 1);      // [NE]
  unsigned short* csr = (unsigned short*)(estage + NE); // [NE]
  float* pe_raw = (float*)(csr + NE);      // [128][32]

  const int* srcA = ei;
  const int* dstA = ei + NE;

  k_init<<<NSCAN, 256, 0, stream>>>(encmn, encmx, WT_pos, bkt_cnt);
  k_f1<<<768, 256, 0, stream>>>(ev, encmn, encmx, dstA, bkt_cnt);
  k_f2<<<9, 512, 0, stream>>>(eigv, alpha, encmn, encmx,
                              Wf, bf, Wl1, Wr1, Wl2, Wr2, Wro, bro,
                              WT_pos, pe_raw, out + (size_t)N*OUT_DIM,
                              WTf, biasf, Wc1, Wc2, WTro, biasro,
                              bkt_cnt, bkt_start, bkt_cursor);
  k_f3<<<NSCATB + 1, 256, 0, stream>>>(srcA, dstA, bkt_cursor, estage,
                                       encmn, encmx, pe_raw, bias_pos);
  k_f4<<<NBK + NTILES, 256, 0, stream>>>(bkt_start, estage, csr, row_ptr,
                                         x, ev, WTf, biasf, WT_pos, bias_pos,
                                         (unsigned short*)h0b);
  k_agg_b<<<(N*64)/256, 256, 0, stream>>>((const unsigned*)h0b, row_ptr, csr, (unsigned*)meanb);
  k_conv<<<NTILES, 256, 0, stream>>>(meanb, h0b, Wc1, bl1, (unsigned short*)h1b);
  k_agg_b<<<(N*64)/256, 256, 0, stream>>>((const unsigned*)h1b, row_ptr, csr, (unsigned*)meanb);
  k_conv_ro<<<NTILES, 256, 0, stream>>>(meanb, h1b, Wc2, bl2, WTro, biasro, out);
}